// Round 10
// baseline (571.134 us; speedup 1.0000x reference)
//
#include <hip/hip_runtime.h>
#include <cstdint>
#include <cstddef>

// ---------- types ----------
typedef __bf16 bf16_t;
typedef __bf16 bf16x8 __attribute__((ext_vector_type(8)));
typedef __bf16 bf16x4 __attribute__((ext_vector_type(4)));
typedef float f32x4 __attribute__((ext_vector_type(4)));

// async global->LDS, 16B per lane. LDS dest must be wave-uniform base + lane*16.
#define GL2LDS16(gptr, lptr)                                                   \
  __builtin_amdgcn_global_load_lds(                                            \
      (__attribute__((address_space(1))) void*)(gptr),                         \
      (__attribute__((address_space(3))) void*)(lptr), 16, 0, 0)

__device__ __forceinline__ float fast_exp2(float x) {
  float r;
  asm volatile("v_exp_f32 %0, %1" : "=v"(r) : "v"(x));
  return r;
}

// ---------- problem constants ----------
#define BATCH 2
#define T_SEQ 2048
#define NH 16
#define NKV 4
#define HD 128
#define EMB 2048
#define KVDIM (NKV * HD)       // 512
#define MROWS (BATCH * T_SEQ)  // 4096

#define BK8 64
#define NT8 (EMB / BK8)  // 32
#define PSTR 72          // attn P row stride (elements)
#define GRIDB 256        // fused grid size (1 block/CU)

// LDS layout (byte offsets into one shared buffer):
//  gemm_qkv phase : 2 x 512*64 bf16 = 131072 B
//  attn phase     : 2 groups x (Ks 32768 + Vs 32768 + Ps 9216) = 149504 B
//  gemm_out phase : 2 groups x (As 16384 + Bs 16384) = 65536 B
#define ATTN_GRP_BYTES 74752
#define SMEM_BYTES 149504

// =====================================================================
// device-scope grid barrier: monotonic u64 counter (memset to 0 before
// launch each replay). Works because counter starts 256-aligned; all
// 256 blocks are co-resident (1/CU by LDS). Release/acquire at agent
// scope covers cross-XCD visibility of global writes between phases.
// =====================================================================
__device__ __forceinline__ void gbar(unsigned long long* cnt) {
  __syncthreads();
  if (threadIdx.x == 0) {
    unsigned long long old = __hip_atomic_fetch_add(
        cnt, 1ULL, __ATOMIC_ACQ_REL, __HIP_MEMORY_SCOPE_AGENT);
    const unsigned long long tgt = (old / GRIDB + 1) * GRIDB;
    while (__hip_atomic_load(cnt, __ATOMIC_ACQUIRE,
                             __HIP_MEMORY_SCOPE_AGENT) < tgt)
      __builtin_amdgcn_s_sleep(2);
  }
  __syncthreads();
}

// =====================================================================
// fused persistent kernel: cvt | gemm_qkv | attn | gemm_out
// =====================================================================
__global__ __launch_bounds__(512, 1)
void fused_all(const float* __restrict__ x,  const float* __restrict__ wq,
               const float* __restrict__ wk, const float* __restrict__ wv,
               const float* __restrict__ wo, float* __restrict__ out,
               bf16_t* __restrict__ xb,  bf16_t* __restrict__ wqb,
               bf16_t* __restrict__ wkb, bf16_t* __restrict__ wvb,
               bf16_t* __restrict__ wob,
               bf16_t* __restrict__ Qb,  bf16_t* __restrict__ Kb,
               bf16_t* __restrict__ Vt,  bf16_t* __restrict__ Yb,
               unsigned long long* __restrict__ cnt, float qalpha)
{
  __shared__ __align__(16) char smem[SMEM_BYTES];

  const int r   = blockIdx.x;          // 0..255
  const int tid = threadIdx.x;         // 0..511

  // =================== phase 1: fp32 -> bf16 convert ===================
  {
    // float4 element counts: x 2097152 | wq 1048576 | wk 262144
    //                        | wv 262144 | wo 1048576  (total 4718592)
    const float4* x4  = (const float4*)x;
    const float4* wq4 = (const float4*)wq;
    const float4* wk4 = (const float4*)wk;
    const float4* wv4 = (const float4*)wv;
    const float4* wo4 = (const float4*)wo;
    bf16x4* xb4  = (bf16x4*)xb;
    bf16x4* wqb4 = (bf16x4*)wqb;
    bf16x4* wkb4 = (bf16x4*)wkb;
    bf16x4* wvb4 = (bf16x4*)wvb;
    bf16x4* wob4 = (bf16x4*)wob;
    const unsigned gtid = r * 512 + tid;
    for (unsigned i = gtid; i < 4718592u; i += GRIDB * 512) {
      const float4* src; bf16x4* dst; unsigned off;
      if (i < 3145728u) {
        if (i < 2097152u) { src = x4;  dst = xb4;  off = i; }
        else              { src = wq4; dst = wqb4; off = i - 2097152u; }
      } else if (i < 3670016u) {
        if (i < 3407872u) { src = wk4; dst = wkb4; off = i - 3145728u; }
        else              { src = wv4; dst = wvb4; off = i - 3407872u; }
      } else              { src = wo4; dst = wob4; off = i - 3670016u; }
      const float4 v = src[off];
      dst[off] = bf16x4{(__bf16)v.x, (__bf16)v.y, (__bf16)v.z, (__bf16)v.w};
    }
  }

  gbar(cnt);

  // =================== phase 2: fused QKV GEMM (R2-exact) ==============
  // blocks 0..191 active; 256x256 8-phase schedule, XOR swizzle,
  // counted vmcnt(6), setprio. N tiles: [0,8) Q | [8,10) K | [10,12) V^T.
  if (r < 192) {
    bf16_t* lds0 = (bf16_t*)smem;
    bf16_t* lds1 = lds0 + 512 * 64;
    bf16_t* ldsp[2] = {lds0, lds1};

    const int lane = tid & 63;
    const int wv_  = tid >> 6;
    const int l15  = lane & 15;
    const int lq   = lane >> 4;

    const int bid0 = r;
    const int bid  = (bid0 & 7) * 24 + (bid0 >> 3);
    const int mt = bid / 12, nt = bid % 12;
    const int m0 = mt * 256;

    const bf16_t* Bmat; int ncol0, seg;
    if (nt < 8)       { Bmat = wqb; ncol0 = nt * 256;        seg = 0; }
    else if (nt < 10) { Bmat = wkb; ncol0 = (nt - 8) * 256;  seg = 1; }
    else              { Bmat = wvb; ncol0 = (nt - 10) * 256; seg = 2; }

    const int wm = (wv_ >> 2) * 128;
    const int wn = (wv_ & 3) * 64;

    f32x4 acc[8][4] = {};

    auto stage = [&](int dbuf, int tsrc, int h) {
      const int k0 = tsrc * BK8;
      const bf16_t* src = (h < 2) ? xb : Bmat;
      const int rbase = (h < 2) ? (m0 + h * 128) : (ncol0 + (h - 2) * 128);
      bf16_t* dst = ldsp[dbuf] + h * 8192;
#pragma unroll
      for (int rr = 0; rr < 2; ++rr) {
        const int c = rr * 512 + tid;
        const int row = c >> 3, p = c & 7;
        const int sb = p ^ (row & 7);
        GL2LDS16(src + (size_t)(rbase + row) * EMB + k0 + sb * 8, dst + c * 8);
      }
    };

    stage(0, 0, 0); stage(0, 0, 1); stage(0, 0, 2); stage(0, 0, 3);
    stage(1, 1, 2); stage(1, 1, 0); stage(1, 1, 3);
    asm volatile("s_waitcnt vmcnt(6)" ::: "memory");
    __builtin_amdgcn_s_barrier();

    bf16x8 a[4][2], b[4][2];

#pragma unroll 1
    for (int tt = 0; tt < NT8; tt += 2) {
#pragma unroll
      for (int u = 0; u < 2; ++u) {
        const int t   = tt + u;
        const int cur = u;
        const int nxt = u ^ 1;
        const int tn1 = (t + 1 < NT8) ? t + 1 : NT8 - 1;
        const int tn2 = (t + 2 < NT8) ? t + 2 : NT8 - 1;

        // phase 1
#pragma unroll
        for (int i = 0; i < 4; ++i) {
          const int row = wm + i * 16 + l15;
#pragma unroll
          for (int ks = 0; ks < 2; ++ks)
            a[i][ks] = *(const bf16x8*)&ldsp[cur][row * 64 + (((ks * 4 + lq) ^ (row & 7)) * 8)];
        }
#pragma unroll
        for (int j = 0; j < 2; ++j) {
          const int row = 256 + wn + j * 16 + l15;
#pragma unroll
          for (int ks = 0; ks < 2; ++ks)
            b[j][ks] = *(const bf16x8*)&ldsp[cur][row * 64 + (((ks * 4 + lq) ^ (row & 7)) * 8)];
        }
        stage(nxt, tn1, 1);
        __builtin_amdgcn_s_barrier();
        __builtin_amdgcn_s_setprio(1);
#pragma unroll
        for (int ks = 0; ks < 2; ++ks)
#pragma unroll
          for (int i = 0; i < 4; ++i)
#pragma unroll
            for (int j = 0; j < 2; ++j)
              acc[i][j] = __builtin_amdgcn_mfma_f32_16x16x32_bf16(a[i][ks], b[j][ks], acc[i][j], 0, 0, 0);
        __builtin_amdgcn_s_setprio(0);
        __builtin_amdgcn_s_barrier();

        // phase 2
#pragma unroll
        for (int j = 2; j < 4; ++j) {
          const int row = 256 + wn + j * 16 + l15;
#pragma unroll
          for (int ks = 0; ks < 2; ++ks)
            b[j][ks] = *(const bf16x8*)&ldsp[cur][row * 64 + (((ks * 4 + lq) ^ (row & 7)) * 8)];
        }
        __builtin_amdgcn_s_barrier();
        __builtin_amdgcn_s_setprio(1);
#pragma unroll
        for (int ks = 0; ks < 2; ++ks)
#pragma unroll
          for (int i = 0; i < 4; ++i)
#pragma unroll
            for (int j = 2; j < 4; ++j)
              acc[i][j] = __builtin_amdgcn_mfma_f32_16x16x32_bf16(a[i][ks], b[j][ks], acc[i][j], 0, 0, 0);
        __builtin_amdgcn_s_setprio(0);
        __builtin_amdgcn_s_barrier();

        // phase 3
#pragma unroll
        for (int i = 0; i < 4; ++i) {
          const int row = wm + (4 + i) * 16 + l15;
#pragma unroll
          for (int ks = 0; ks < 2; ++ks)
            a[i][ks] = *(const bf16x8*)&ldsp[cur][row * 64 + (((ks * 4 + lq) ^ (row & 7)) * 8)];
        }
        stage(cur, tn2, 2);
        __builtin_amdgcn_s_barrier();
        __builtin_amdgcn_s_setprio(1);
#pragma unroll
        for (int ks = 0; ks < 2; ++ks)
#pragma unroll
          for (int i = 0; i < 4; ++i)
#pragma unroll
            for (int j = 2; j < 4; ++j)
              acc[4 + i][j] = __builtin_amdgcn_mfma_f32_16x16x32_bf16(a[i][ks], b[j][ks], acc[4 + i][j], 0, 0, 0);
        __builtin_amdgcn_s_setprio(0);
        __builtin_amdgcn_s_barrier();

        // phase 4
        stage(cur, tn2, 0);
        stage(cur, tn2, 3);
        __builtin_amdgcn_s_barrier();
        __builtin_amdgcn_s_setprio(1);
#pragma unroll
        for (int ks = 0; ks < 2; ++ks)
#pragma unroll
          for (int i = 0; i < 4; ++i)
#pragma unroll
            for (int j = 0; j < 2; ++j)
              acc[4 + i][j] = __builtin_amdgcn_mfma_f32_16x16x32_bf16(a[i][ks], b[j][ks], acc[4 + i][j], 0, 0, 0);
        __builtin_amdgcn_s_setprio(0);
        asm volatile("s_waitcnt vmcnt(6)" ::: "memory");
        __builtin_amdgcn_s_barrier();
      }
    }
    asm volatile("s_waitcnt vmcnt(0)" ::: "memory");

    if (seg == 0) {
#pragma unroll
      for (int i = 0; i < 8; ++i) {
        const int rbase = m0 + wm + i * 16 + lq * 4;
#pragma unroll
        for (int j = 0; j < 4; ++j) {
          const int col = ncol0 + wn + j * 16 + l15;
#pragma unroll
          for (int rr = 0; rr < 4; ++rr)
            Qb[(size_t)(rbase + rr) * EMB + col] = (bf16_t)(acc[i][j][rr] * qalpha);
        }
      }
    } else if (seg == 1) {
#pragma unroll
      for (int i = 0; i < 8; ++i) {
        const int rbase = m0 + wm + i * 16 + lq * 4;
#pragma unroll
        for (int j = 0; j < 4; ++j) {
          const int col = ncol0 + wn + j * 16 + l15;
#pragma unroll
          for (int rr = 0; rr < 4; ++rr)
            Kb[(size_t)(rbase + rr) * KVDIM + col] = (bf16_t)acc[i][j][rr];
        }
      }
    } else {
      const int bb = m0 >> 11;
      const int mloc0 = (m0 & 2047) + wm + lq * 4;
#pragma unroll
      for (int i = 0; i < 8; ++i) {
        const int mloc = mloc0 + i * 16;
#pragma unroll
        for (int j = 0; j < 4; ++j) {
          const int d = ncol0 + wn + j * 16 + l15;
          *(bf16x4*)(Vt + (size_t)(bb * KVDIM + d) * T_SEQ + mloc) =
              bf16x4{(__bf16)acc[i][j][0], (__bf16)acc[i][j][1],
                     (__bf16)acc[i][j][2], (__bf16)acc[i][j][3]};
        }
      }
    }
  }

  gbar(cnt);

  // =================== phase 3: flash attention (R0-exact) =============
  // Two independent 4-wave groups per block; group = batch b. Both
  // groups share x (= r&15) -> identical qt sequence -> identical
  // barrier counts, so full-block __syncthreads is a valid sync.
  {
    const int grp = tid >> 8;            // 0/1 = batch
    const int tg  = tid & 255;
    const int lane = tg & 63;
    const int wv_  = tg >> 6;
    const int l15  = lane & 15;
    const int lq   = lane >> 4;
    const int xq = r & 15;
    const int h  = r >> 4;               // 0..15
    const int b  = grp;
    const int hkv = h >> 2;

    bf16_t* Ksg = (bf16_t*)(smem + grp * ATTN_GRP_BYTES);      // 2*8192 elems
    bf16_t* Vsg = Ksg + 2 * 8192;                              // 2*8192 elems
    bf16_t* Psw = Vsg + 2 * 8192 + wv_ * 16 * PSTR;            // 16*72 elems

    auto stage = [&](int kt, int bufsel) {
      const int base_t = b * T_SEQ + kt * 64;
#pragma unroll
      for (int rr = 0; rr < 4; ++rr) {
        const int c = rr * 256 + tg;
        const int row = c >> 4, p = c & 15;
        const int sb = p ^ (row & 7);
        GL2LDS16(Kb + (size_t)(base_t + row) * KVDIM + hkv * HD + sb * 8,
                 Ksg + bufsel * 8192 + c * 8);
      }
#pragma unroll
      for (int rr = 0; rr < 4; ++rr) {
        const int c = rr * 256 + tg;
        const int row = c >> 3, p = c & 7;
        const int sb = p ^ (row & 7);
        GL2LDS16(Vt + (size_t)(b * KVDIM + hkv * HD + row) * T_SEQ + kt * 64 + sb * 8,
                 Vsg + bufsel * 8192 + c * 8);
      }
    };

#pragma unroll 1
    for (int ph = 0; ph < 2; ++ph) {
      const int qt = ph ? xq : (31 - xq);
      const int nkt = qt + 1;
      const int qabs = qt * 64 + wv_ * 16 + l15;

      bf16x8 qf[4];
      {
        const bf16_t* qp = Qb + ((size_t)(b * T_SEQ + qabs) * NH + h) * HD + lq * 8;
#pragma unroll
        for (int ds = 0; ds < 4; ++ds)
          qf[ds] = *(const bf16x8*)(qp + ds * 32);
      }

      float l_part = 0.f;
      f32x4 o[8];
#pragma unroll
      for (int nb = 0; nb < 8; ++nb) o[nb] = f32x4{0.f, 0.f, 0.f, 0.f};

      __syncthreads();
      stage(0, 0);

      for (int kt = 0; kt < nkt; ++kt) {
        const int cur = kt & 1;
        __syncthreads();
        if (kt + 1 < nkt) stage(kt + 1, cur ^ 1);

        f32x4 s[4];
#pragma unroll
        for (int nb = 0; nb < 4; ++nb) {
          s[nb] = f32x4{0.f, 0.f, 0.f, 0.f};
          const int row = nb * 16 + l15;
          const int r7  = row & 7;
#pragma unroll
          for (int ds = 0; ds < 4; ++ds) {
            const bf16x8 kf = *(const bf16x8*)&Ksg[cur * 8192 + row * 128 + (((ds * 4 + lq) ^ r7) * 8)];
            s[nb] = __builtin_amdgcn_mfma_f32_16x16x32_bf16(kf, qf[ds], s[nb], 0, 0, 0);
          }
        }

        const bool dia = (kt == nkt - 1);
#pragma unroll
        for (int nb = 0; nb < 4; ++nb) {
          const int kvb = kt * 64 + nb * 16 + lq * 4;
          float p0, p1, p2, p3;
          if (dia) {
            p0 = (kvb + 0 <= qabs) ? fast_exp2(s[nb][0]) : 0.f;
            p1 = (kvb + 1 <= qabs) ? fast_exp2(s[nb][1]) : 0.f;
            p2 = (kvb + 2 <= qabs) ? fast_exp2(s[nb][2]) : 0.f;
            p3 = (kvb + 3 <= qabs) ? fast_exp2(s[nb][3]) : 0.f;
          } else {
            p0 = fast_exp2(s[nb][0]);
            p1 = fast_exp2(s[nb][1]);
            p2 = fast_exp2(s[nb][2]);
            p3 = fast_exp2(s[nb][3]);
          }
          l_part += (p0 + p1) + (p2 + p3);
          *(bf16x4*)(Psw + l15 * PSTR + nb * 16 + lq * 4) =
              bf16x4{(__bf16)p0, (__bf16)p1, (__bf16)p2, (__bf16)p3};
        }

        asm volatile("s_waitcnt lgkmcnt(0)" ::: "memory");

#pragma unroll
        for (int ks = 0; ks < 2; ++ks) {
          const bf16x8 pf = *(const bf16x8*)(Psw + l15 * PSTR + ks * 32 + lq * 8);
#pragma unroll
          for (int nb = 0; nb < 8; ++nb) {
            const int row = nb * 16 + l15;
            const bf16x8 vf = *(const bf16x8*)&Vsg[cur * 8192 + row * 64 + (((ks * 4 + lq) ^ (row & 7)) * 8)];
            o[nb] = __builtin_amdgcn_mfma_f32_16x16x32_bf16(vf, pf, o[nb], 0, 0, 0);
          }
        }
      }

      float lt = l_part;
      lt += __shfl_xor(lt, 16);
      lt += __shfl_xor(lt, 32);
      const float inv = 1.f / lt;
      bf16_t* yp = Yb + ((size_t)(b * T_SEQ + qabs) * NH + h) * HD + lq * 4;
#pragma unroll
      for (int nb = 0; nb < 8; ++nb) {
        *(bf16x4*)(yp + nb * 16) = bf16x4{(__bf16)(o[nb][0] * inv), (__bf16)(o[nb][1] * inv),
                                          (__bf16)(o[nb][2] * inv), (__bf16)(o[nb][3] * inv)};
      }
    }
  }

  gbar(cnt);

  // =================== phase 4: out-projection GEMM ====================
  // Two 4-wave groups per block; virtual block v = r*2+g over (16 N x
  // 32 M) grid. Identical 32-iter loops -> barrier counts match.
  {
    const int grp = tid >> 8;
    const int tg  = tid & 255;
    const int lane = tg & 63;
    const int wv_  = tg >> 6;
    const int v = r * 2 + grp;
    const int m0 = (v >> 4) * 128;
    const int n0 = (v & 15) * 128;
    const int wm = (wv_ >> 1) * 64;
    const int wn = (wv_ & 1) * 64;
    const int l15 = lane & 15;
    const int lq  = lane >> 4;

    bf16_t* As = (bf16_t*)(smem + grp * 32768);       // 128*64 elems
    bf16_t* Bs = As + 128 * 64;

    f32x4 acc[4][4] = {};
    const int srow = tg >> 3;
    const int scol = (tg & 7) * 8;

    for (int k0 = 0; k0 < EMB; k0 += 64) {
#pragma unroll
      for (int rr = 0; rr < 4; ++rr) {
        const int row = rr * 32 + srow;
        GL2LDS16(Yb + (size_t)(m0 + row) * EMB + k0 + scol, As + row * 64 + scol);
      }
#pragma unroll
      for (int rr = 0; rr < 4; ++rr) {
        const int row = rr * 32 + srow;
        GL2LDS16(wob + (size_t)(n0 + row) * EMB + k0 + scol, Bs + row * 64 + scol);
      }
      __syncthreads();

#pragma unroll
      for (int ks = 0; ks < 2; ++ks) {
        const int kc = ks * 32 + lq * 8;
        bf16x8 af[4], bf[4];
#pragma unroll
        for (int i = 0; i < 4; ++i)
          af[i] = *(const bf16x8*)(As + (wm + i * 16 + l15) * 64 + kc);
#pragma unroll
        for (int j = 0; j < 4; ++j)
          bf[j] = *(const bf16x8*)(Bs + (wn + j * 16 + l15) * 64 + kc);
#pragma unroll
        for (int i = 0; i < 4; ++i)
#pragma unroll
          for (int j = 0; j < 4; ++j)
            acc[i][j] = __builtin_amdgcn_mfma_f32_16x16x32_bf16(af[i], bf[j], acc[i][j], 0, 0, 0);
      }
      __syncthreads();
    }

#pragma unroll
    for (int i = 0; i < 4; ++i) {
      const int rbase = m0 + wm + i * 16 + lq * 4;
#pragma unroll
      for (int j = 0; j < 4; ++j) {
        const int col = n0 + wn + j * 16 + l15;
#pragma unroll
        for (int rr = 0; rr < 4; ++rr)
          out[(size_t)(rbase + rr) * EMB + col] = acc[i][j][rr];
      }
    }
  }
}

// =====================================================================
// launch: memset barrier counter (capture-legal) + ONE fused kernel.
// =====================================================================
extern "C" void kernel_launch(void* const* d_in, const int* in_sizes, int n_in,
                              void* d_out, int out_size, void* d_ws, size_t ws_size,
                              hipStream_t stream) {
  const float* x  = (const float*)d_in[0];
  const float* wq = (const float*)d_in[1];
  const float* wk = (const float*)d_in[2];
  const float* wv = (const float*)d_in[3];
  const float* wo = (const float*)d_in[4];
  float* out = (float*)d_out;

  const size_t n_x  = (size_t)MROWS * EMB;
  const size_t n_wq = (size_t)EMB * EMB;
  const size_t n_wk = (size_t)KVDIM * EMB;

  unsigned long long* cnt = (unsigned long long*)d_ws;   // 16-B header
  bf16_t* xb  = (bf16_t*)((char*)d_ws + 16);
  bf16_t* wqb = xb  + n_x;
  bf16_t* wkb = wqb + n_wq;
  bf16_t* wvb = wkb + n_wk;
  bf16_t* wob = wvb + n_wk;
  bf16_t* Qb  = wob + n_wq;                  // 4096*2048
  bf16_t* Kb  = Qb + (size_t)MROWS * EMB;    // 4096*512
  bf16_t* Vtb = Kb + (size_t)MROWS * KVDIM;  // (B*512)*2048 transposed V
  bf16_t* Yb  = Vtb + (size_t)MROWS * KVDIM; // 4096*2048

  hipMemsetAsync(cnt, 0, 8, stream);

  const float qalpha = 0.08838834764831845f * 1.4426950408889634f;
  fused_all<<<dim3(GRIDB), dim3(512), 0, stream>>>(
      x, wq, wk, wv, wo, out,
      xb, wqb, wkb, wvb, wob, Qb, Kb, Vtb, Yb, cnt, qalpha);
}